// Round 1
// baseline (743.342 us; speedup 1.0000x reference)
//
#include <hip/hip_runtime.h>

#define NN 50000
#define EE 800000
#define LL 3
#define HH 4
#define CC 16
#define DD 64
#define GG 512
#define GRAPH_DIM 128

// ---------------------------------------------------------------------------
// utility: zero int / float ranges (avoid hipMemsetAsync capture concerns)
// ---------------------------------------------------------------------------
__global__ void zero_i32(int* p, int n) {
    int i = blockIdx.x * blockDim.x + threadIdx.x;
    if (i < n) p[i] = 0;
}
__global__ void zero_f32(float* p, int n) {
    int i = blockIdx.x * blockDim.x + threadIdx.x;
    if (i < n) p[i] = 0.f;
}

// ---------------------------------------------------------------------------
// CSR build: histogram of dst, exclusive scan, scatter (src, attr) by dst
// ---------------------------------------------------------------------------
__global__ void hist_kernel(const int* __restrict__ dst, int* __restrict__ counts) {
    int e = blockIdx.x * blockDim.x + threadIdx.x;
    if (e < EE) atomicAdd(&counts[dst[e]], 1);
}

// single block, 1024 threads; counts -> row_ptr (exclusive), writepos = row_ptr copy
__global__ __launch_bounds__(1024) void scan_kernel(const int* __restrict__ counts,
                                                    int* __restrict__ row_ptr,
                                                    int* __restrict__ writepos) {
    __shared__ int wsum[16];
    int t = threadIdx.x, lane = t & 63, wid = t >> 6;
    int base = 0;
    for (int start = 0; start < NN; start += 1024) {
        int idx = start + t;
        int val = (idx < NN) ? counts[idx] : 0;
        int x = val;
        #pragma unroll
        for (int o = 1; o < 64; o <<= 1) {
            int y = __shfl_up(x, o);
            if (lane >= o) x += y;
        }
        if (lane == 63) wsum[wid] = x;
        __syncthreads();
        if (wid == 0) {
            int s = (lane < 16) ? wsum[lane] : 0;
            #pragma unroll
            for (int o = 1; o < 16; o <<= 1) {
                int y = __shfl_up(s, o);
                if (lane >= o) s += y;
            }
            if (lane < 16) wsum[lane] = s;
        }
        __syncthreads();
        int excl = x - val + base + (wid > 0 ? wsum[wid - 1] : 0);
        if (idx < NN) { row_ptr[idx] = excl; writepos[idx] = excl; }
        int total = wsum[15];
        __syncthreads();   // wsum reused next iteration
        base += total;
    }
    if (t == 0) row_ptr[NN] = base;   // == EE
}

__global__ void scatter_kernel(const int* __restrict__ ei, const float* __restrict__ attr,
                               int* __restrict__ writepos,
                               int* __restrict__ src_s, float* __restrict__ attr_s) {
    int e = blockIdx.x * blockDim.x + threadIdx.x;
    if (e < EE) {
        int s = ei[e];
        int d = ei[EE + e];
        int p = atomicAdd(&writepos[d], 1);
        src_s[p] = s;
        attr_s[p] = attr[e];
    }
}

// ---------------------------------------------------------------------------
// fused node GEMM: q,k,v,skip = h @ {Wq,Wk,Wv,Ws} + {bq,bk,bv,bs}
// block = 256 threads; 32-node tile in LDS; thread t -> (matrix t/64, col t%64)
// ---------------------------------------------------------------------------
__global__ __launch_bounds__(256) void node_gemm(
    const float* __restrict__ hx,
    const float* __restrict__ Wq, const float* __restrict__ bq,
    const float* __restrict__ Wk, const float* __restrict__ bk,
    const float* __restrict__ Wv, const float* __restrict__ bv,
    const float* __restrict__ Ws, const float* __restrict__ bs,
    float* __restrict__ q, float* __restrict__ k,
    float* __restrict__ v, float* __restrict__ sk)
{
    __shared__ float xs[32 * 64];
    int t = threadIdx.x;
    int node0 = blockIdx.x * 32;

    // stage 32x64 f32 tile, vectorized
    const float4* src4 = (const float4*)(hx + (size_t)node0 * 64);
    float4* dst4 = (float4*)xs;
    #pragma unroll
    for (int r = 0; r < 2; ++r) {
        int i4 = t + r * 256;                  // 0..511 float4s
        int node = node0 + (i4 >> 4);
        float4 val = make_float4(0.f, 0.f, 0.f, 0.f);
        if (node < NN) val = src4[i4];
        dst4[i4] = val;
    }
    __syncthreads();

    int mat = t >> 6, j = t & 63;
    const float* W = (mat == 0) ? Wq : (mat == 1) ? Wk : (mat == 2) ? Wv : Ws;
    const float* B = (mat == 0) ? bq : (mat == 1) ? bk : (mat == 2) ? bv : bs;
    float* O       = (mat == 0) ? q  : (mat == 1) ? k  : (mat == 2) ? v  : sk;

    float wcol[64];
    #pragma unroll
    for (int i = 0; i < 64; ++i) wcol[i] = W[i * 64 + j];
    float bj = B[j];

    for (int n = 0; n < 32; ++n) {
        int node = node0 + n;
        if (node >= NN) break;
        float acc = bj;
        const float4* xr = (const float4*)(xs + n * 64);
        #pragma unroll
        for (int i4 = 0; i4 < 16; ++i4) {
            float4 xv = xr[i4];
            acc = fmaf(xv.x, wcol[4 * i4 + 0], acc);
            acc = fmaf(xv.y, wcol[4 * i4 + 1], acc);
            acc = fmaf(xv.z, wcol[4 * i4 + 2], acc);
            acc = fmaf(xv.w, wcol[4 * i4 + 3], acc);
        }
        O[(size_t)node * 64 + j] = acc;
    }
}

// ---------------------------------------------------------------------------
// node-centric attention aggregate: one wave per dst node, lane = channel.
// out[n] = (sum_e exp(s_e)*(v[src]+e)) / (sum_e exp(s_e) + 1e-16) + skip[n]
// (softmax shift-invariance: max-subtraction dropped; |score| is O(1) here)
// ---------------------------------------------------------------------------
__global__ __launch_bounds__(256) void node_attn(
    const float* __restrict__ q, const float* __restrict__ k,
    const float* __restrict__ v, const float* __restrict__ sk,
    const float* __restrict__ We,
    const int* __restrict__ row_ptr, const int* __restrict__ src_s,
    const float* __restrict__ attr_s,
    float* __restrict__ out, int do_relu, int do_pool,
    const int* __restrict__ batch,
    float* __restrict__ gsum, float* __restrict__ gcnt)
{
    int node = blockIdx.x * 4 + (threadIdx.x >> 6);
    int lane = threadIdx.x & 63;
    if (node >= NN) return;

    size_t nb = (size_t)node * 64;
    float qv = q[nb + lane];
    float skv = sk[nb + lane];
    float we = We[lane];
    int p0 = row_ptr[node];
    int p1 = row_ptr[node + 1];

    float acc = 0.f, den = 0.f;
    for (int p = p0; p < p1; ++p) {
        int s = src_s[p];
        float a = attr_s[p];
        float ew = a * we;
        size_t sb = (size_t)s * 64 + lane;
        float kj = k[sb] + ew;
        float pr = qv * kj;
        pr += __shfl_xor(pr, 1);
        pr += __shfl_xor(pr, 2);
        pr += __shfl_xor(pr, 4);
        pr += __shfl_xor(pr, 8);          // per-head dot over 16 channels
        float ex = __expf(pr * 0.25f);    // / sqrt(C)
        float vj = v[sb] + ew;
        acc = fmaf(ex, vj, acc);
        den += ex;
    }
    float o = acc / (den + 1e-16f) + skv;
    if (do_relu) o = fmaxf(o, 0.f);
    out[nb + lane] = o;

    if (do_pool) {
        int b = batch[node];
        atomicAdd(&gsum[(size_t)b * 64 + lane], o);
        if (lane == 0) atomicAdd(&gcnt[b], 1.f);
    }
}

// ---------------------------------------------------------------------------
// mean-pool finalize + 3-layer MLP head; one block (128 thr) per graph
// ---------------------------------------------------------------------------
__global__ __launch_bounds__(128) void pool_mlp(
    const float* __restrict__ gsum, const float* __restrict__ gcnt,
    const float* __restrict__ W1, const float* __restrict__ b1,
    const float* __restrict__ W2, const float* __restrict__ b2,
    const float* __restrict__ W3, const float* __restrict__ b3,
    float* __restrict__ out)
{
    __shared__ float g[64];
    __shared__ float h1s[64];
    __shared__ float h2s[16];
    int b = blockIdx.x, t = threadIdx.x;

    if (t < 64) {
        float c = gcnt[b];
        g[t] = gsum[(size_t)b * 64 + t] / fmaxf(c, 1.f);
    }
    __syncthreads();
    if (t < 64) {
        float a = b1[t];
        #pragma unroll
        for (int i = 0; i < 64; ++i) a = fmaf(g[i], W1[i * 64 + t], a);
        h1s[t] = fmaxf(a, 0.f);
    }
    __syncthreads();
    if (t < 16) {
        float a = b2[t];
        #pragma unroll
        for (int i = 0; i < 64; ++i) a = fmaf(h1s[i], W2[i * 16 + t], a);
        h2s[t] = fmaxf(a, 0.f);
    }
    __syncthreads();
    float a = b3[t];
    #pragma unroll
    for (int i = 0; i < 16; ++i) a = fmaf(h2s[i], W3[i * 128 + t], a);
    out[(size_t)b * 128 + t] = a;
}

// ---------------------------------------------------------------------------
extern "C" void kernel_launch(void* const* d_in, const int* in_sizes, int n_in,
                              void* d_out, int out_size, void* d_ws, size_t ws_size,
                              hipStream_t stream) {
    const float* x         = (const float*)d_in[0];
    const float* edge_attr = (const float*)d_in[1];
    const int*   edge_index= (const int*)d_in[2];
    const int*   batch     = (const int*)d_in[3];
    const float* Wq   = (const float*)d_in[4];
    const float* bq   = (const float*)d_in[5];
    const float* Wk   = (const float*)d_in[6];
    const float* bk   = (const float*)d_in[7];
    const float* Wv   = (const float*)d_in[8];
    const float* bv   = (const float*)d_in[9];
    const float* We   = (const float*)d_in[10];
    const float* Wsk  = (const float*)d_in[11];
    const float* bsk  = (const float*)d_in[12];
    const float* W1   = (const float*)d_in[13];
    const float* b1   = (const float*)d_in[14];
    const float* W2   = (const float*)d_in[15];
    const float* b2   = (const float*)d_in[16];
    const float* W3   = (const float*)d_in[17];
    const float* b3   = (const float*)d_in[18];

    float* out        = (float*)d_out;
    float* node_emb   = out;                         // N*64
    float* graph_feat = out + (size_t)NN * 64;       // G*128

    // workspace carve (all f32/i32, 4B aligned; base is malloc-aligned)
    float* wsf    = (float*)d_ws;
    float* q      = wsf;
    float* k      = q    + (size_t)NN * 64;
    float* v      = k    + (size_t)NN * 64;
    float* skp    = v    + (size_t)NN * 64;
    float* h      = skp  + (size_t)NN * 64;
    float* attr_s = h    + (size_t)NN * 64;
    int*   src_s  = (int*)(attr_s + EE);
    int*   row_ptr= src_s + EE;
    int*   wpos   = row_ptr + (NN + 1);
    float* gsum   = (float*)(wpos + NN);
    float* gcnt   = gsum + (size_t)GG * 64;

    // ---- CSR build (dst-sorted edges); reused by all 3 layers ----
    zero_i32<<<(NN + 255) / 256, 256, 0, stream>>>(wpos, NN);
    zero_f32<<<(GG * 64 + GG + 255) / 256, 256, 0, stream>>>(gsum, GG * 64 + GG);
    hist_kernel<<<(EE + 255) / 256, 256, 0, stream>>>(edge_index + EE, wpos);
    scan_kernel<<<1, 1024, 0, stream>>>(wpos, row_ptr, wpos);
    scatter_kernel<<<(EE + 255) / 256, 256, 0, stream>>>(edge_index, edge_attr,
                                                         wpos, src_s, attr_s);

    int gemm_grid = (NN + 31) / 32;
    int attn_grid = (NN + 3) / 4;

    const float* layer_in = x;
    for (int l = 0; l < LL; ++l) {
        const float* Wq_l = Wq + (size_t)l * 64 * 64;
        const float* Wk_l = Wk + (size_t)l * 64 * 64;
        const float* Wv_l = Wv + (size_t)l * 64 * 64;
        const float* Ws_l = Wsk + (size_t)l * 64 * 64;
        const float* bq_l = bq + (size_t)l * 64;
        const float* bk_l = bk + (size_t)l * 64;
        const float* bv_l = bv + (size_t)l * 64;
        const float* bs_l = bsk + (size_t)l * 64;
        const float* We_l = We + (size_t)l * 64;

        node_gemm<<<gemm_grid, 256, 0, stream>>>(layer_in,
            Wq_l, bq_l, Wk_l, bk_l, Wv_l, bv_l, Ws_l, bs_l,
            q, k, v, skp);

        int last = (l == LL - 1);
        float* dst_h = last ? node_emb : h;
        node_attn<<<attn_grid, 256, 0, stream>>>(q, k, v, skp, We_l,
            row_ptr, src_s, attr_s,
            dst_h, /*relu=*/!last, /*pool=*/last,
            batch, gsum, gcnt);

        layer_in = h;
    }

    pool_mlp<<<GG, 128, 0, stream>>>(gsum, gcnt, W1, b1, W2, b2, W3, b3, graph_feat);
}

// Round 2
// 631.200 us; speedup vs baseline: 1.1777x; 1.1777x over previous
//
#include <hip/hip_runtime.h>

#define NN 50000
#define EE 800000
#define LL 3
#define HH 4
#define CC 16
#define DD 64
#define GG 512
#define GRAPH_DIM 128

// ---------------------------------------------------------------------------
// utility: zero int / float ranges
// ---------------------------------------------------------------------------
__global__ void zero_i32(int* p, int n) {
    int i = blockIdx.x * blockDim.x + threadIdx.x;
    if (i < n) p[i] = 0;
}
__global__ void zero_f32(float* p, int n) {
    int i = blockIdx.x * blockDim.x + threadIdx.x;
    if (i < n) p[i] = 0.f;
}

// ---------------------------------------------------------------------------
// CSR build: histogram of dst, exclusive scan, scatter (src, attr) by dst
// ---------------------------------------------------------------------------
__global__ void hist_kernel(const int* __restrict__ dst, int* __restrict__ counts) {
    int e = blockIdx.x * blockDim.x + threadIdx.x;
    if (e < EE) atomicAdd(&counts[dst[e]], 1);
}

__global__ __launch_bounds__(1024) void scan_kernel(const int* __restrict__ counts,
                                                    int* __restrict__ row_ptr,
                                                    int* __restrict__ writepos) {
    __shared__ int wsum[16];
    int t = threadIdx.x, lane = t & 63, wid = t >> 6;
    int base = 0;
    for (int start = 0; start < NN; start += 1024) {
        int idx = start + t;
        int val = (idx < NN) ? counts[idx] : 0;
        int x = val;
        #pragma unroll
        for (int o = 1; o < 64; o <<= 1) {
            int y = __shfl_up(x, o);
            if (lane >= o) x += y;
        }
        if (lane == 63) wsum[wid] = x;
        __syncthreads();
        if (wid == 0) {
            int s = (lane < 16) ? wsum[lane] : 0;
            #pragma unroll
            for (int o = 1; o < 16; o <<= 1) {
                int y = __shfl_up(s, o);
                if (lane >= o) s += y;
            }
            if (lane < 16) wsum[lane] = s;
        }
        __syncthreads();
        int excl = x - val + base + (wid > 0 ? wsum[wid - 1] : 0);
        if (idx < NN) { row_ptr[idx] = excl; writepos[idx] = excl; }
        int total = wsum[15];
        __syncthreads();
        base += total;
    }
    if (t == 0) row_ptr[NN] = base;
}

__global__ void scatter_kernel(const int* __restrict__ ei, const float* __restrict__ attr,
                               int* __restrict__ writepos,
                               int* __restrict__ src_s, float* __restrict__ attr_s) {
    int e = blockIdx.x * blockDim.x + threadIdx.x;
    if (e < EE) {
        int s = ei[e];
        int d = ei[EE + e];
        int p = atomicAdd(&writepos[d], 1);
        src_s[p] = s;
        attr_s[p] = attr[e];
    }
}

// ---------------------------------------------------------------------------
// fused node GEMM: q,k,v,skip = h @ {Wq,Wk,Wv,Ws} + {bq,bk,bv,bs}
// ---------------------------------------------------------------------------
__global__ __launch_bounds__(256) void node_gemm(
    const float* __restrict__ hx,
    const float* __restrict__ Wq, const float* __restrict__ bq,
    const float* __restrict__ Wk, const float* __restrict__ bk,
    const float* __restrict__ Wv, const float* __restrict__ bv,
    const float* __restrict__ Ws, const float* __restrict__ bs,
    float* __restrict__ q, float* __restrict__ k,
    float* __restrict__ v, float* __restrict__ sk)
{
    __shared__ float xs[32 * 64];
    int t = threadIdx.x;
    int node0 = blockIdx.x * 32;

    const float4* src4 = (const float4*)(hx + (size_t)node0 * 64);
    float4* dst4 = (float4*)xs;
    #pragma unroll
    for (int r = 0; r < 2; ++r) {
        int i4 = t + r * 256;
        int node = node0 + (i4 >> 4);
        float4 val = make_float4(0.f, 0.f, 0.f, 0.f);
        if (node < NN) val = src4[i4];
        dst4[i4] = val;
    }
    __syncthreads();

    int mat = t >> 6, j = t & 63;
    const float* W = (mat == 0) ? Wq : (mat == 1) ? Wk : (mat == 2) ? Wv : Ws;
    const float* B = (mat == 0) ? bq : (mat == 1) ? bk : (mat == 2) ? bv : bs;
    float* O       = (mat == 0) ? q  : (mat == 1) ? k  : (mat == 2) ? v  : sk;

    float wcol[64];
    #pragma unroll
    for (int i = 0; i < 64; ++i) wcol[i] = W[i * 64 + j];
    float bj = B[j];

    for (int n = 0; n < 32; ++n) {
        int node = node0 + n;
        if (node >= NN) break;
        float acc = bj;
        const float4* xr = (const float4*)(xs + n * 64);
        #pragma unroll
        for (int i4 = 0; i4 < 16; ++i4) {
            float4 xv = xr[i4];
            acc = fmaf(xv.x, wcol[4 * i4 + 0], acc);
            acc = fmaf(xv.y, wcol[4 * i4 + 1], acc);
            acc = fmaf(xv.z, wcol[4 * i4 + 2], acc);
            acc = fmaf(xv.w, wcol[4 * i4 + 3], acc);
        }
        O[(size_t)node * 64 + j] = acc;
    }
}

// ---------------------------------------------------------------------------
// node-centric attention aggregate: one wave per dst node, lane = channel.
// 4-way ILP unroll over edges: 8 independent gathers + 4 interleaved
// shuffle-reduction chains per group to hide gather + DS-swizzle latency.
// Algebra hoisted:  score = (q.k + a*(q.we))/4 with q.we loop-invariant;
//                   sum ex*(v+a*we) = sum(ex*v) + we*sum(ex*a)
// ---------------------------------------------------------------------------
__global__ __launch_bounds__(256) void node_attn(
    const float* __restrict__ q, const float* __restrict__ k,
    const float* __restrict__ v, const float* __restrict__ sk,
    const float* __restrict__ We,
    const int* __restrict__ row_ptr, const int* __restrict__ src_s,
    const float* __restrict__ attr_s,
    float* __restrict__ out, int do_relu, int do_pool,
    const int* __restrict__ batch,
    float* __restrict__ gsum, float* __restrict__ gcnt)
{
    int node = blockIdx.x * 4 + (threadIdx.x >> 6);
    int lane = threadIdx.x & 63;
    if (node >= NN) return;

    size_t nb = (size_t)node * 64;
    float qv = q[nb + lane];
    float skv = sk[nb + lane];
    float we = We[lane];

    // loop-invariant per-head dot  qw = sum_{c in head} q*we  (same in 16 lanes)
    float qw = qv * we;
    qw += __shfl_xor(qw, 1);
    qw += __shfl_xor(qw, 2);
    qw += __shfl_xor(qw, 4);
    qw += __shfl_xor(qw, 8);

    int p0 = row_ptr[node];
    int p1 = row_ptr[node + 1];

    float acc = 0.f, den = 0.f, saw = 0.f;
    int p = p0;
    for (; p + 4 <= p1; p += 4) {
        int s0 = src_s[p + 0], s1 = src_s[p + 1];
        int s2 = src_s[p + 2], s3 = src_s[p + 3];
        float a0 = attr_s[p + 0], a1 = attr_s[p + 1];
        float a2 = attr_s[p + 2], a3 = attr_s[p + 3];
        size_t b0 = (size_t)s0 * 64 + lane, b1 = (size_t)s1 * 64 + lane;
        size_t b2 = (size_t)s2 * 64 + lane, b3 = (size_t)s3 * 64 + lane;
        float k0 = k[b0], k1 = k[b1], k2 = k[b2], k3 = k[b3];
        float v0 = v[b0], v1 = v[b1], v2 = v[b2], v3 = v[b3];

        float r0 = qv * k0, r1 = qv * k1, r2 = qv * k2, r3 = qv * k3;
        r0 += __shfl_xor(r0, 1); r1 += __shfl_xor(r1, 1);
        r2 += __shfl_xor(r2, 1); r3 += __shfl_xor(r3, 1);
        r0 += __shfl_xor(r0, 2); r1 += __shfl_xor(r1, 2);
        r2 += __shfl_xor(r2, 2); r3 += __shfl_xor(r3, 2);
        r0 += __shfl_xor(r0, 4); r1 += __shfl_xor(r1, 4);
        r2 += __shfl_xor(r2, 4); r3 += __shfl_xor(r3, 4);
        r0 += __shfl_xor(r0, 8); r1 += __shfl_xor(r1, 8);
        r2 += __shfl_xor(r2, 8); r3 += __shfl_xor(r3, 8);

        float e0 = __expf(fmaf(a0, qw, r0) * 0.25f);
        float e1 = __expf(fmaf(a1, qw, r1) * 0.25f);
        float e2 = __expf(fmaf(a2, qw, r2) * 0.25f);
        float e3 = __expf(fmaf(a3, qw, r3) * 0.25f);

        acc = fmaf(e0, v0, acc); den += e0; saw = fmaf(e0, a0, saw);
        acc = fmaf(e1, v1, acc); den += e1; saw = fmaf(e1, a1, saw);
        acc = fmaf(e2, v2, acc); den += e2; saw = fmaf(e2, a2, saw);
        acc = fmaf(e3, v3, acc); den += e3; saw = fmaf(e3, a3, saw);
    }
    for (; p < p1; ++p) {
        int s = src_s[p];
        float a = attr_s[p];
        size_t sb = (size_t)s * 64 + lane;
        float kj = k[sb];
        float vj = v[sb];
        float r = qv * kj;
        r += __shfl_xor(r, 1);
        r += __shfl_xor(r, 2);
        r += __shfl_xor(r, 4);
        r += __shfl_xor(r, 8);
        float ex = __expf(fmaf(a, qw, r) * 0.25f);
        acc = fmaf(ex, vj, acc);
        den += ex;
        saw = fmaf(ex, a, saw);
    }

    float o = (acc + saw * we) / (den + 1e-16f) + skv;
    if (do_relu) o = fmaxf(o, 0.f);
    out[nb + lane] = o;

    if (do_pool) {
        int b = batch[node];
        atomicAdd(&gsum[(size_t)b * 64 + lane], o);
        if (lane == 0) atomicAdd(&gcnt[b], 1.f);
    }
}

// ---------------------------------------------------------------------------
// mean-pool finalize + 3-layer MLP head; one block (128 thr) per graph
// ---------------------------------------------------------------------------
__global__ __launch_bounds__(128) void pool_mlp(
    const float* __restrict__ gsum, const float* __restrict__ gcnt,
    const float* __restrict__ W1, const float* __restrict__ b1,
    const float* __restrict__ W2, const float* __restrict__ b2,
    const float* __restrict__ W3, const float* __restrict__ b3,
    float* __restrict__ out)
{
    __shared__ float g[64];
    __shared__ float h1s[64];
    __shared__ float h2s[16];
    int b = blockIdx.x, t = threadIdx.x;

    if (t < 64) {
        float c = gcnt[b];
        g[t] = gsum[(size_t)b * 64 + t] / fmaxf(c, 1.f);
    }
    __syncthreads();
    if (t < 64) {
        float a = b1[t];
        #pragma unroll
        for (int i = 0; i < 64; ++i) a = fmaf(g[i], W1[i * 64 + t], a);
        h1s[t] = fmaxf(a, 0.f);
    }
    __syncthreads();
    if (t < 16) {
        float a = b2[t];
        #pragma unroll
        for (int i = 0; i < 64; ++i) a = fmaf(h1s[i], W2[i * 16 + t], a);
        h2s[t] = fmaxf(a, 0.f);
    }
    __syncthreads();
    float a = b3[t];
    #pragma unroll
    for (int i = 0; i < 16; ++i) a = fmaf(h2s[i], W3[i * 128 + t], a);
    out[(size_t)b * 128 + t] = a;
}

// ---------------------------------------------------------------------------
extern "C" void kernel_launch(void* const* d_in, const int* in_sizes, int n_in,
                              void* d_out, int out_size, void* d_ws, size_t ws_size,
                              hipStream_t stream) {
    const float* x         = (const float*)d_in[0];
    const float* edge_attr = (const float*)d_in[1];
    const int*   edge_index= (const int*)d_in[2];
    const int*   batch     = (const int*)d_in[3];
    const float* Wq   = (const float*)d_in[4];
    const float* bq   = (const float*)d_in[5];
    const float* Wk   = (const float*)d_in[6];
    const float* bk   = (const float*)d_in[7];
    const float* Wv   = (const float*)d_in[8];
    const float* bv   = (const float*)d_in[9];
    const float* We   = (const float*)d_in[10];
    const float* Wsk  = (const float*)d_in[11];
    const float* bsk  = (const float*)d_in[12];
    const float* W1   = (const float*)d_in[13];
    const float* b1   = (const float*)d_in[14];
    const float* W2   = (const float*)d_in[15];
    const float* b2   = (const float*)d_in[16];
    const float* W3   = (const float*)d_in[17];
    const float* b3   = (const float*)d_in[18];

    float* out        = (float*)d_out;
    float* node_emb   = out;                         // N*64
    float* graph_feat = out + (size_t)NN * 64;       // G*128

    float* wsf    = (float*)d_ws;
    float* q      = wsf;
    float* k      = q    + (size_t)NN * 64;
    float* v      = k    + (size_t)NN * 64;
    float* skp    = v    + (size_t)NN * 64;
    float* h      = skp  + (size_t)NN * 64;
    float* attr_s = h    + (size_t)NN * 64;
    int*   src_s  = (int*)(attr_s + EE);
    int*   row_ptr= src_s + EE;
    int*   wpos   = row_ptr + (NN + 1);
    float* gsum   = (float*)(wpos + NN);
    float* gcnt   = gsum + (size_t)GG * 64;

    // ---- CSR build (dst-sorted edges); reused by all 3 layers ----
    zero_i32<<<(NN + 255) / 256, 256, 0, stream>>>(wpos, NN);
    zero_f32<<<(GG * 64 + GG + 255) / 256, 256, 0, stream>>>(gsum, GG * 64 + GG);
    hist_kernel<<<(EE + 255) / 256, 256, 0, stream>>>(edge_index + EE, wpos);
    scan_kernel<<<1, 1024, 0, stream>>>(wpos, row_ptr, wpos);
    scatter_kernel<<<(EE + 255) / 256, 256, 0, stream>>>(edge_index, edge_attr,
                                                         wpos, src_s, attr_s);

    int gemm_grid = (NN + 31) / 32;
    int attn_grid = (NN + 3) / 4;

    const float* layer_in = x;
    for (int l = 0; l < LL; ++l) {
        const float* Wq_l = Wq + (size_t)l * 64 * 64;
        const float* Wk_l = Wk + (size_t)l * 64 * 64;
        const float* Wv_l = Wv + (size_t)l * 64 * 64;
        const float* Ws_l = Wsk + (size_t)l * 64 * 64;
        const float* bq_l = bq + (size_t)l * 64;
        const float* bk_l = bk + (size_t)l * 64;
        const float* bv_l = bv + (size_t)l * 64;
        const float* bs_l = bsk + (size_t)l * 64;
        const float* We_l = We + (size_t)l * 64;

        node_gemm<<<gemm_grid, 256, 0, stream>>>(layer_in,
            Wq_l, bq_l, Wk_l, bk_l, Wv_l, bv_l, Ws_l, bs_l,
            q, k, v, skp);

        int last = (l == LL - 1);
        float* dst_h = last ? node_emb : h;
        node_attn<<<attn_grid, 256, 0, stream>>>(q, k, v, skp, We_l,
            row_ptr, src_s, attr_s,
            dst_h, /*relu=*/!last, /*pool=*/last,
            batch, gsum, gcnt);

        layer_in = h;
    }

    pool_mlp<<<GG, 128, 0, stream>>>(gsum, gcnt, W1, b1, W2, b2, W3, b3, graph_feat);
}